// Round 3
// baseline (385.941 us; speedup 1.0000x reference)
//
#include <hip/hip_runtime.h>
#include <hip/hip_bf16.h>

#define DEV static __device__ __forceinline__

typedef short frag8 __attribute__((ext_vector_type(8)));
typedef float accf4 __attribute__((ext_vector_type(4)));

// Problem constants
// B=8, P=576, D=1024, H=16, HD=64, HID=4096, BP=4608, BH=128

DEV unsigned short f2bf(float f){
  union { float f; unsigned int u; } v; v.f = f;
  unsigned int r = v.u + 0x7fffu + ((v.u >> 16) & 1u);
  return (unsigned short)(r >> 16);
}

DEV void gload16(const void* g, void* l){
  __builtin_amdgcn_global_load_lds((const __attribute__((address_space(1))) void*)g,
                                   (__attribute__((address_space(3))) void*)l, 16, 0, 0);
}

DEV float gelu_tanh(float x){
  float u = 0.7978845608028654f * (x + 0.044715f * x * x * x);
  float e = __expf(2.0f * u);
  float th = 1.0f - 2.0f / (e + 1.0f);   // tanh(u), inf-safe
  return 0.5f * x * (1.0f + th);
}

// ---------------- weight cast + transpose: W[K,N] f32 -> Wt[N,K] bf16 ----------------
__global__ __launch_bounds__(256) void wtrans(const float* __restrict__ W,
                                              unsigned short* __restrict__ Wt,
                                              int K, int N){
  __shared__ float t[32][33];
  const int n0 = blockIdx.x * 32, k0 = blockIdx.y * 32;
  const int tx = threadIdx.x, ty = threadIdx.y;   // (32,8)
  #pragma unroll
  for (int i = 0; i < 4; i++)
    t[ty + i*8][tx] = W[(long)(k0 + ty + i*8) * N + n0 + tx];
  __syncthreads();
  #pragma unroll
  for (int i = 0; i < 4; i++)
    Wt[(long)(n0 + ty + i*8) * K + k0 + tx] = f2bf(t[tx][ty + i*8]);
}

// ---------------- LayerNorm over D=1024 rows: f32 in -> bf16 out ----------------
__global__ __launch_bounds__(256) void ln_rows(const float* __restrict__ in,
                                               const float* __restrict__ g,
                                               const float* __restrict__ beta,
                                               unsigned short* __restrict__ out){
  const long row = blockIdx.x;
  const int t = threadIdx.x;
  const float4 v = ((const float4*)(in + row * 1024))[t];
  float s  = v.x + v.y + v.z + v.w;
  float s2 = v.x*v.x + v.y*v.y + v.z*v.z + v.w*v.w;
  #pragma unroll
  for (int o = 32; o; o >>= 1){ s += __shfl_xor(s, o); s2 += __shfl_xor(s2, o); }
  __shared__ float rs[4], rq[4];
  const int wv = t >> 6;
  if ((t & 63) == 0){ rs[wv] = s; rq[wv] = s2; }
  __syncthreads();
  s  = rs[0] + rs[1] + rs[2] + rs[3];
  s2 = rq[0] + rq[1] + rq[2] + rq[3];
  const float mean = s * (1.f/1024.f);
  const float inv = rsqrtf(s2 * (1.f/1024.f) - mean*mean + 1e-6f);
  const float4 gv = ((const float4*)g)[t];
  const float4 bv = ((const float4*)beta)[t];
  ushort4 o4;
  o4.x = f2bf((v.x - mean)*inv*gv.x + bv.x);
  o4.y = f2bf((v.y - mean)*inv*gv.y + bv.y);
  o4.z = f2bf((v.z - mean)*inv*gv.z + bv.z);
  o4.w = f2bf((v.w - mean)*inv*gv.w + bv.w);
  *(ushort4*)(out + row * 1024 + t * 4) = o4;
}

// ---------------- per-head QK-LayerNorm prep ----------------
// qkvf: [4608, 3072] f32.  Qn/Kn: [BH=128][576][64] bf16 (Q scaled by HD^-0.5)
__global__ __launch_bounds__(256) void qkln(const float* __restrict__ qkvf,
    const float* __restrict__ qg, const float* __restrict__ qb,
    const float* __restrict__ kg, const float* __restrict__ kb,
    unsigned short* __restrict__ Qn, unsigned short* __restrict__ Kn){
  const int lane = threadIdx.x;                       // 64 = HD
  const int r = blockIdx.x * 4 + threadIdx.y;         // row in [0, 73728)
  const int bh = r / 576, p = r - bh * 576;
  const int b = bh >> 4, h = bh & 15;
  const long base = ((long)(b * 576 + p)) * 3072 + h * 64 + lane;
  float q = qkvf[base];
  float k = qkvf[base + 1024];
  float sq = q, sq2 = q*q, sk = k, sk2 = k*k;
  #pragma unroll
  for (int o = 32; o; o >>= 1){
    sq += __shfl_xor(sq, o); sq2 += __shfl_xor(sq2, o);
    sk += __shfl_xor(sk, o); sk2 += __shfl_xor(sk2, o);
  }
  const float mq = sq * (1.f/64.f), vq = sq2 * (1.f/64.f) - mq*mq;
  const float mk = sk * (1.f/64.f), vk = sk2 * (1.f/64.f) - mk*mk;
  const float qn = ((q - mq) * rsqrtf(vq + 1e-6f) * qg[lane] + qb[lane]) * 0.125f;
  const float kn =  (k - mk) * rsqrtf(vk + 1e-6f) * kg[lane] + kb[lane];
  const long ob = (long)r * 64 + lane;
  Qn[ob] = f2bf(qn);
  Kn[ob] = f2bf(kn);
}

// ---------------- V transpose per head: qkvf v-part -> Vt [BH][64][576] bf16 ----------------
__global__ __launch_bounds__(256) void v_trans(const float* __restrict__ qkvf,
                                               unsigned short* __restrict__ Vt){
  const int bh = blockIdx.x, pt = blockIdx.y;   // pt: 0..8 (64 p's each)
  const int b = bh >> 4, h = bh & 15;
  __shared__ float tile[64][65];
  const int t = threadIdx.x;
  #pragma unroll
  for (int i = 0; i < 16; i++){
    int idx = i * 256 + t; int p = idx >> 6, d = idx & 63;
    tile[p][d] = qkvf[((long)(b * 576) + pt * 64 + p) * 3072 + 2048 + h * 64 + d];
  }
  __syncthreads();
  #pragma unroll
  for (int i = 0; i < 16; i++){
    int idx = i * 256 + t; int d = idx >> 6, p = idx & 63;
    Vt[((long)bh * 64 + d) * 576 + pt * 64 + p] = f2bf(tile[p][d]);
  }
}

// ---------------- attention: one block = one (bh, 16-q-row tile) ----------------
__global__ __launch_bounds__(256) void attn_k(const unsigned short* __restrict__ Qn,
                                              const unsigned short* __restrict__ Kn,
                                              const unsigned short* __restrict__ Vt,
                                              float* __restrict__ O){
  const int qb = blockIdx.x;   // 0..35
  const int bh = blockIdx.y;   // 0..127
  const int b = bh >> 4, h = bh & 15;
  const int tid = threadIdx.x, wv = tid >> 6, lane = tid & 63;
  const int fr = lane & 15, fq = lane >> 4;
  __shared__ float S[16][578];
  __shared__ __align__(16) unsigned short Pl[16][584];

  // Q fragments (rows qb*16+fr, all 64 d): same in every wave
  const unsigned short* qbase = Qn + ((long)bh * 576 + qb * 16 + fr) * 64;
  frag8 qf0 = *(const frag8*)(qbase + fq * 8);
  frag8 qf1 = *(const frag8*)(qbase + 32 + fq * 8);

  // QK^T: wave wv handles key tiles wv, wv+4, ...
  for (int i = 0; i < 9; i++){
    const int kt = wv + 4 * i;
    const unsigned short* kbase = Kn + ((long)bh * 576 + kt * 16 + fr) * 64;
    frag8 kf0 = *(const frag8*)(kbase + fq * 8);
    frag8 kf1 = *(const frag8*)(kbase + 32 + fq * 8);
    accf4 a = {0.f, 0.f, 0.f, 0.f};
    a = __builtin_amdgcn_mfma_f32_16x16x32_bf16(qf0, kf0, a, 0, 0, 0);
    a = __builtin_amdgcn_mfma_f32_16x16x32_bf16(qf1, kf1, a, 0, 0, 0);
    #pragma unroll
    for (int rr = 0; rr < 4; rr++) S[fq * 4 + rr][kt * 16 + fr] = a[rr];
  }
  __syncthreads();

  // softmax: 16 threads per row
  {
    const int row = tid >> 4, cid = tid & 15;
    float vals[36];
    float mx = -1e30f;
    #pragma unroll
    for (int i = 0; i < 36; i++){ vals[i] = S[row][cid + 16 * i]; mx = fmaxf(mx, vals[i]); }
    #pragma unroll
    for (int o = 8; o; o >>= 1) mx = fmaxf(mx, __shfl_xor(mx, o));
    float sum = 0.f;
    #pragma unroll
    for (int i = 0; i < 36; i++){ vals[i] = __expf(vals[i] - mx); sum += vals[i]; }
    #pragma unroll
    for (int o = 8; o; o >>= 1) sum += __shfl_xor(sum, o);
    const float rsum = 1.f / sum;
    #pragma unroll
    for (int i = 0; i < 36; i++) Pl[row][cid + 16 * i] = f2bf(vals[i] * rsum);
  }
  __syncthreads();

  // PV: wave wv owns d-tile wv (16 cols of 64)
  accf4 oa = {0.f, 0.f, 0.f, 0.f};
  for (int kt = 0; kt < 18; kt++){
    frag8 pf = *(const frag8*)&Pl[fr][kt * 32 + fq * 8];
    const unsigned short* vb = Vt + ((long)bh * 64 + wv * 16 + fr) * 576 + kt * 32 + fq * 8;
    frag8 vf = *(const frag8*)vb;
    oa = __builtin_amdgcn_mfma_f32_16x16x32_bf16(pf, vf, oa, 0, 0, 0);
  }
  #pragma unroll
  for (int rr = 0; rr < 4; rr++){
    const long orow = (long)b * 576 + qb * 16 + fq * 4 + rr;
    O[orow * 1024 + h * 64 + wv * 16 + fr] = oa[rr];
  }
}

// ---------------- GEMM: C[M,N] = A[M,K] * Bt[N,K]^T, bf16 in, f32 acc ----------------
// EPI 0: C=f32 plain.  EPI 1: Cf = resid + (acc + bias)*ls.  EPI 2: Cb = bf16(gelu(acc + bias)).
template<int EPI>
__global__ __launch_bounds__(256) void gemm_bt(
    const unsigned short* __restrict__ A, const unsigned short* __restrict__ Bt,
    float* __restrict__ Cf, unsigned short* __restrict__ Cb,
    const float* __restrict__ bias, const float* __restrict__ ls,
    const float* __restrict__ resid, int M, int N, int K)
{
  __shared__ __align__(16) unsigned short As[128 * 32];
  __shared__ __align__(16) unsigned short Bs[128 * 32];
  const int tid = threadIdx.x;
  const int wave = tid >> 6, lane = tid & 63;
  const int fr = lane & 15, fq = lane >> 4;
  const int wr = wave >> 1, wc = wave & 1;
  const long rowbase = (long)blockIdx.y * 128;
  const long colbase = (long)blockIdx.x * 128;

  accf4 acc[4][4];
  const accf4 zero = {0.f, 0.f, 0.f, 0.f};
  #pragma unroll
  for (int m = 0; m < 4; m++)
    #pragma unroll
    for (int n = 0; n < 4; n++) acc[m][n] = zero;

  // staging: 2 chunks of 64 rows per tile; linear LDS row-major [128][32]
  const unsigned short* a0 = A + (rowbase + (tid >> 2)) * (long)K + (tid & 3) * 8;
  const unsigned short* a1 = a0 + 64l * K;
  const unsigned short* b0 = Bt + (colbase + (tid >> 2)) * (long)K + (tid & 3) * 8;
  const unsigned short* b1 = b0 + 64l * K;
  unsigned short* lA0 = &As[wave * 512];
  unsigned short* lA1 = &As[2048 + wave * 512];
  unsigned short* lB0 = &Bs[wave * 512];
  unsigned short* lB1 = &Bs[2048 + wave * 512];

  for (int k0 = 0; k0 < K; k0 += 32){
    __syncthreads();
    gload16(a0 + k0, lA0);
    gload16(a1 + k0, lA1);
    gload16(b0 + k0, lB0);
    gload16(b1 + k0, lB1);
    __syncthreads();
    frag8 af[4], bf[4];
    #pragma unroll
    for (int m = 0; m < 4; m++) af[m] = *(const frag8*)&As[(wr*64 + m*16 + fr)*32 + fq*8];
    #pragma unroll
    for (int n = 0; n < 4; n++) bf[n] = *(const frag8*)&Bs[(wc*64 + n*16 + fr)*32 + fq*8];
    #pragma unroll
    for (int m = 0; m < 4; m++)
      #pragma unroll
      for (int n = 0; n < 4; n++)
        acc[m][n] = __builtin_amdgcn_mfma_f32_16x16x32_bf16(af[m], bf[n], acc[m][n], 0, 0, 0);
  }

  #pragma unroll
  for (int m = 0; m < 4; m++){
    const long rb = rowbase + wr * 64 + m * 16 + fq * 4;
    #pragma unroll
    for (int n = 0; n < 4; n++){
      const long cb = colbase + wc * 64 + n * 16 + fr;
      #pragma unroll
      for (int r = 0; r < 4; r++){
        const long idx = (rb + r) * N + cb;
        const float v = acc[m][n][r];
        if constexpr (EPI == 0){
          Cf[idx] = v;
        } else if constexpr (EPI == 1){
          Cf[idx] = resid[idx] + (v + bias[cb]) * ls[cb];
        } else {
          Cb[idx] = f2bf(gelu_tanh(v + bias[cb]));
        }
      }
    }
  }
}

extern "C" void kernel_launch(void* const* d_in, const int* in_sizes, int n_in,
                              void* d_out, int out_size, void* d_ws, size_t ws_size,
                              hipStream_t stream){
  (void)in_sizes; (void)n_in; (void)out_size; (void)ws_size;
  const float* x      = (const float*)d_in[0];
  const float* w_qkv  = (const float*)d_in[1];
  const float* q_g    = (const float*)d_in[2];
  const float* q_b    = (const float*)d_in[3];
  const float* k_g    = (const float*)d_in[4];
  const float* k_b    = (const float*)d_in[5];
  const float* o_g    = (const float*)d_in[6];
  const float* o_b    = (const float*)d_in[7];
  const float* w_proj = (const float*)d_in[8];
  const float* b_proj = (const float*)d_in[9];
  const float* ln1_g  = (const float*)d_in[10];
  const float* ln1_b  = (const float*)d_in[11];
  const float* ln2_g  = (const float*)d_in[12];
  const float* ln2_b  = (const float*)d_in[13];
  const float* w1     = (const float*)d_in[14];
  const float* b1     = (const float*)d_in[15];
  const float* w2     = (const float*)d_in[16];
  const float* b2     = (const float*)d_in[17];
  const float* ls1    = (const float*)d_in[18];
  const float* ls2    = (const float*)d_in[19];
  float* out = (float*)d_out;

  char* ws = (char*)d_ws;
  size_t off = 0;
  auto alloc = [&](size_t bytes)->void*{
    void* p = ws + off; off += (bytes + 255) & ~(size_t)255; return p;
  };
  unsigned short* wqkvT  = (unsigned short*)alloc(3072l*1024*2);
  unsigned short* wprojT = (unsigned short*)alloc(1024l*1024*2);
  unsigned short* w1T    = (unsigned short*)alloc(4096l*1024*2);
  unsigned short* w2T    = (unsigned short*)alloc(1024l*4096*2);
  unsigned short* xnA    = (unsigned short*)alloc(4608l*1024*2);   // xn1 / on / xn2 (sequential liveness)
  float*          qkvf   = (float*)alloc(4608l*3072*4);
  unsigned short* Qn     = (unsigned short*)alloc(73728l*64*2);
  unsigned short* Kn     = (unsigned short*)alloc(73728l*64*2);
  unsigned short* Vt     = (unsigned short*)alloc(73728l*64*2);
  // overlays on dead qkvf region:
  float*          attnO  = qkvf;                                             // 18.9 MB
  unsigned short* hbf    = (unsigned short*)((char*)qkvf + 4608l*1024*4);    // 37.7 MB

  // weights -> bf16 B^T
  wtrans<<<dim3(3072/32, 1024/32), dim3(32,8), 0, stream>>>(w_qkv,  wqkvT,  1024, 3072);
  wtrans<<<dim3(1024/32, 1024/32), dim3(32,8), 0, stream>>>(w_proj, wprojT, 1024, 1024);
  wtrans<<<dim3(4096/32, 1024/32), dim3(32,8), 0, stream>>>(w1,     w1T,    1024, 4096);
  wtrans<<<dim3(1024/32, 4096/32), dim3(32,8), 0, stream>>>(w2,     w2T,    4096, 1024);

  // attention branch
  ln_rows<<<4608, 256, 0, stream>>>(x, ln1_g, ln1_b, xnA);
  gemm_bt<0><<<dim3(24,36), 256, 0, stream>>>(xnA, wqkvT, qkvf, nullptr,
                                              nullptr, nullptr, nullptr, 4608, 3072, 1024);
  qkln<<<18432, dim3(64,4), 0, stream>>>(qkvf, q_g, q_b, k_g, k_b, Qn, Kn);
  v_trans<<<dim3(128,9), 256, 0, stream>>>(qkvf, Vt);
  attn_k<<<dim3(36,128), 256, 0, stream>>>(Qn, Kn, Vt, attnO);
  ln_rows<<<4608, 256, 0, stream>>>(attnO, o_g, o_b, xnA);
  gemm_bt<1><<<dim3(8,36), 256, 0, stream>>>(xnA, wprojT, out, nullptr,
                                             b_proj, ls1, x, 4608, 1024, 1024);
  // MLP branch
  ln_rows<<<4608, 256, 0, stream>>>(out, ln2_g, ln2_b, xnA);
  gemm_bt<2><<<dim3(32,36), 256, 0, stream>>>(xnA, w1T, nullptr, hbf,
                                              b1, nullptr, nullptr, 4608, 4096, 1024);
  gemm_bt<1><<<dim3(8,36), 256, 0, stream>>>(hbf, w2T, out, nullptr,
                                             b2, ls2, out, 4608, 1024, 4096);
}